// Round 1
// baseline (346.383 us; speedup 1.0000x reference)
//
#include <hip/hip_runtime.h>

#define BATCH  16
#define SEQ    4096
#define DIM    64
#define NHASH  8
#define NCHUNK 512   // chunks per batch row (NHASH * SEQ / 64)
#define SB     72    // bf16 LDS row stride: 72*2=144 B, 16B-aligned for b128

typedef __attribute__((ext_vector_type(8))) short short8;   // 8 bf16 (4 VGPR)
typedef __attribute__((ext_vector_type(4))) float floatx4;  // MFMA C/D

__device__ __forceinline__ float trunc_hi(float a) {
    return __uint_as_float(__float_as_uint(a) & 0xffff0000u);
}
__device__ __forceinline__ unsigned pack_hi2(float a, float b) {
    return (__float_as_uint(a) >> 16) | (__float_as_uint(b) & 0xffff0000u);
}
// round-to-nearest bf16 pack: unbiased, max rel err 2^-9 (trunc was 2^-8 + bias)
__device__ __forceinline__ unsigned pack_rn2(float a, float b) {
    unsigned ua = __float_as_uint(a) + 0x8000u;
    unsigned ub = __float_as_uint(b) + 0x8000u;
    return (ua >> 16) | (ub & 0xffff0000u);
}
// 16 fp32 -> 16 bf16 (round-to-nearest) stored as 2x uint4
__device__ __forceinline__ void hi16_store_rn(const float* xs, short* dst) {
    unsigned hd[8];
#pragma unroll
    for (int u = 0; u < 8; ++u) hd[u] = pack_rn2(xs[2*u], xs[2*u + 1]);
    *(uint4*)(dst)     = make_uint4(hd[0], hd[1], hd[2], hd[3]);
    *(uint4*)(dst + 8) = make_uint4(hd[4], hd[5], hd[6], hd[7]);
}
// split 8 fp32 -> bf16 hi/lo short8 fragments in registers (exact split: trunc)
__device__ __forceinline__ void split8_frag(const float* xs, short8* hi, short8* lo) {
    union { unsigned u[4]; short8 s; } H, L;
#pragma unroll
    for (int u = 0; u < 4; ++u) {
        float a = xs[2*u], b = xs[2*u + 1];
        H.u[u] = pack_hi2(a, b);
        L.u[u] = pack_hi2(a - trunc_hi(a), b - trunc_hi(b));
    }
    *hi = H.s; *lo = L.s;
}

// ---------------------------------------------------------------------------
// Kernel 1: LSH hashing (rot slice in LDS, broadcast ds_read + dense fp32 FMA,
// 2 tokens/thread, 2 h'/thread). NEW: zero-inits the fused Onum/Dsum
// accumulators (17 MB) at entry -- fire-and-forget stores hidden under the
// compute-bound hash loop; stream order makes them visible to kernel 3.
// ---------------------------------------------------------------------------
__global__ __launch_bounds__(256, 2) void lsh_hash_kernel(
    const float* __restrict__ qk, const float* __restrict__ rot,
    int* __restrict__ buckets, float4* __restrict__ zinit)
{
    {   // zero Onum (1,048,576 f4) + Dsum (16,384 f4): 131072 threads total
        float4 z = make_float4(0.f, 0.f, 0.f, 0.f);
        int t = blockIdx.x * 256 + (int)threadIdx.x;
#pragma unroll
        for (int j = 0; j < 8; ++j) zinit[(size_t)j * 131072 + t] = z;
        if (t < 16384) zinit[(size_t)8 * 131072 + t] = z;
    }

    __shared__ float rs[64 * 128];     // [f][h'][i] = f*128 + h'*32 + i (32 KB)
    int tid = threadIdx.x;
    int tb   = blockIdx.x >> 1;        // 256-token tile
    int hsel = blockIdx.x & 1;         // h half: h = hsel*4 + h'

    {   // stage rot slice: 2048 float4, 8 per thread, coalesced
        const float4* rg = (const float4*)rot;
#pragma unroll
        for (int j = 0; j < 8; ++j) {
            int idx4 = j * 256 + tid;
            int f = idx4 >> 5, r4 = idx4 & 31;
            ((float4*)rs)[idx4] = rg[f * 64 + hsel * 32 + r4];
        }
    }
    __syncthreads();

    int tt = tid & 127;
    int hh = tid >> 7;                 // 0/1, wave-uniform
    int gid0 = tb * 256 + tt;
    int gid1 = gid0 + 128;
    const float* q0 = qk + (size_t)gid0 * DIM;
    const float* q1 = qk + (size_t)gid1 * DIM;

#pragma unroll
    for (int h0 = 0; h0 < 2; ++h0) {
        int hp = hh * 2 + h0;
        const float* rbase = rs + hp * 32;
        float a0[32], a1[32];
#pragma unroll
        for (int i = 0; i < 32; ++i) { a0[i] = 0.f; a1[i] = 0.f; }
#pragma unroll 1
        for (int ft = 0; ft < 8; ++ft) {
            float qa[8], qb[8];
            *(float4*)&qa[0] = *(const float4*)(q0 + ft * 8);
            *(float4*)&qa[4] = *(const float4*)(q0 + ft * 8 + 4);
            *(float4*)&qb[0] = *(const float4*)(q1 + ft * 8);
            *(float4*)&qb[4] = *(const float4*)(q1 + ft * 8 + 4);
#pragma unroll
            for (int f8 = 0; f8 < 8; ++f8) {
                const float* rp = rbase + (ft * 8 + f8) * 128;
                float x = qa[f8], y = qb[f8];
#pragma unroll
                for (int i = 0; i < 32; ++i) {
                    float r = rp[i];
                    a0[i] = fmaf(x, r, a0[i]);
                    a1[i] = fmaf(y, r, a1[i]);
                }
            }
        }
        int h = hsel * 4 + hp;
        {
            float best = a0[0]; int bi = 0;
#pragma unroll
            for (int i = 1; i < 32; ++i) { if (a0[i] > best) { best = a0[i]; bi = i; } }
#pragma unroll
            for (int i = 0; i < 32; ++i) { float nv = -a0[i]; if (nv > best) { best = nv; bi = i + 32; } }
            int b = gid0 >> 12, t = gid0 & 4095;
            buckets[((size_t)b * NHASH + h) * SEQ + t] = bi;
        }
        {
            float best = a1[0]; int bi = 0;
#pragma unroll
            for (int i = 1; i < 32; ++i) { if (a1[i] > best) { best = a1[i]; bi = i; } }
#pragma unroll
            for (int i = 0; i < 32; ++i) { float nv = -a1[i]; if (nv > best) { best = nv; bi = i + 32; } }
            int b = gid1 >> 12, t = gid1 & 4095;
            buckets[((size_t)b * NHASH + h) * SEQ + t] = bi;
        }
    }
}

// ---------------------------------------------------------------------------
// Kernel 2: stable counting sort per (b,h), 4-wave (unchanged).
// ---------------------------------------------------------------------------
__global__ __launch_bounds__(256) void lsh_sort_kernel(
    const int* __restrict__ buckets, int* __restrict__ st)
{
    __shared__ int hist[256 * 65];
    __shared__ int seg[256];
    __shared__ int base[64];

    int bh = blockIdx.x;
    int tid = threadIdx.x;
    int w = tid >> 6, lane = tid & 63;

    for (int i = tid; i < 256 * 65; i += 256) hist[i] = 0;

    int myb[16];
    {
        const int4* bp4 = (const int4*)(buckets + (size_t)bh * SEQ);
#pragma unroll
        for (int u4 = 0; u4 < 4; ++u4) {
            int4 bb = bp4[tid * 4 + u4];
            myb[u4*4+0] = bb.x; myb[u4*4+1] = bb.y;
            myb[u4*4+2] = bb.z; myb[u4*4+3] = bb.w;
        }
    }
    __syncthreads();
    int* hrow = &hist[tid * 65];
#pragma unroll
    for (int u = 0; u < 16; ++u) hrow[myb[u]] += 1;
    __syncthreads();

    {
        int run = 0;
        for (int tp = 0; tp < 64; ++tp) {
            int idx = (w * 64 + tp) * 65 + lane;
            int c0 = hist[idx];
            hist[idx] = run;
            run += c0;
        }
        seg[w * 64 + lane] = run;
    }
    __syncthreads();
    if (tid < 64) {
        int s0 = seg[lane], s1 = seg[64 + lane], s2 = seg[128 + lane], s3 = seg[192 + lane];
        seg[lane] = 0; seg[64 + lane] = s0;
        seg[128 + lane] = s0 + s1; seg[192 + lane] = s0 + s1 + s2;
        int tot = s0 + s1 + s2 + s3;
        int x = tot;
#pragma unroll
        for (int d = 1; d < 64; d <<= 1) {
            int y = __shfl_up(x, d, 64);
            if (lane >= d) x += y;
        }
        base[lane] = x - tot;
    }
    __syncthreads();

    int* op = st + (size_t)bh * SEQ;
#pragma unroll
    for (int u = 0; u < 16; ++u) {
        int bb = myb[u];
        int local = hrow[bb];
        hrow[bb] = local + 1;
        int pos = base[bb] + seg[w * 64 + bb] + local;
        op[pos] = tid * 16 + u;
    }
}

// ---------------------------------------------------------------------------
// Kernel 3: MFMA attention. R11 changes (LDS pipe was the bottleneck at
// ~65% busy; 27.9 KB = 5 blocks/CU):
//  - P stored HI-ONLY with round-to-nearest (unbiased +-2^-9 rel). Attention
//    is near-uniform here (dots std ~0.125, N_eff ~128 keys) so the P error
//    averages to ~1e-4 at the output. Kills the Psp tile AND 16 ds_write_b16
//    + 2 ds_read_b128 + 8 MFMAs per half. LDS 27.9 -> 18.7 KB -> 8 blocks/CU.
//  - K/V staging switched to RN packing: removes the truncation bias
//    (~1e-3 rel systematic shrink) -> buys back absmax headroom.
//  - Epilogue: fused combine numerator. out = (sum_h o_h)/(sum_h D_h), so we
//    atomically add un-normalized O and D into token-major accumulators
//    (17 MB, L2-resident, 8 writers/line over the whole kernel). Kills the
//    134 MB Obuf round-trip.
// LDS insts/half ~58 -> ~40; MFMA/half 32 -> 24.
// ---------------------------------------------------------------------------
__global__ __launch_bounds__(256, 8) void lsh_attn_kernel(
    const float* __restrict__ qk, const float* __restrict__ v,
    const int* __restrict__ st, float* __restrict__ Onum, float* __restrict__ Dsum)
{
    __shared__ short Khi[64 * SB];     // staged K-hi; doubles as P-hi after dots
    __shared__ short Vhi[64 * SB];     // transposed: [dim][key], hi only
    __shared__ int   tk[64];

    short* Phi = Khi;

    int tid  = threadIdx.x;
    int lane = tid & 63;
    int w    = tid >> 6;          // wave id = query-strip / V key-group
    int quad = lane >> 4;
    int l15  = lane & 15;

    int bc = blockIdx.x;
    int b = bc >> 9, c = bc & (NCHUNK - 1);
    int cm = (c + NCHUNK - 1) & (NCHUNK - 1);

    const int*   stb = st + (size_t)b * (NHASH * SEQ);
    const float* qkb = qk + (size_t)b * SEQ * DIM;
    const float* vb  = v  + (size_t)b * SEQ * DIM;

    // ---- Q fragments in registers (both halves use the same Q) ----
    short8 qH[2], qL[2];
    {
        int qt = stb[c * 64 + 16 * w + l15];       // this lane's Q row token
        const float* qp = qkb + (size_t)qt * DIM + 8 * quad;
        float xs[8];
#pragma unroll
        for (int kb = 0; kb < 2; ++kb) {
            *(float4*)&xs[0] = *(const float4*)(qp + 32 * kb);
            *(float4*)&xs[4] = *(const float4*)(qp + 32 * kb + 4);
            split8_frag(xs, &qH[kb], &qL[kb]);
        }
    }
    // mask row-ids for this lane's C-fragment rows (quad*4+r), both halves
    int tqr[4];
#pragma unroll
    for (int r = 0; r < 4; ++r) tqr[r] = stb[c * 64 + 16 * w + quad * 4 + r];

    float   Dacc[4] = {0.f, 0.f, 0.f, 0.f};
    floatx4 oacc[4];
#pragma unroll
    for (int a = 0; a < 4; ++a) oacc[a] = (floatx4){0.f, 0.f, 0.f, 0.f};

    for (int half = 0; half < 2; ++half) {
        int ck = half ? cm : c;
        __syncthreads();              // prev-half P/V LDS reads complete

        {   // stage K (L2-normalized, hi-only RN): 4 threads/row, 16 dims each
            int r = tid >> 2, s = tid & 3;
            int trow = stb[ck * 64 + r];
            if (s == 0) tk[r] = trow;
            const float4* k4 = (const float4*)(qkb + (size_t)trow * DIM + s * 16);
            float xs[16];
            *(float4*)&xs[0]  = k4[0];
            *(float4*)&xs[4]  = k4[1];
            *(float4*)&xs[8]  = k4[2];
            *(float4*)&xs[12] = k4[3];
            float ss = 0.f;
#pragma unroll
            for (int u = 0; u < 16; ++u) ss += xs[u] * xs[u];
            ss += __shfl_xor(ss, 1);
            ss += __shfl_xor(ss, 2);
            float sc = 1.0f / fmaxf(sqrtf(ss), 1e-12f);
#pragma unroll
            for (int u = 0; u < 16; ++u) xs[u] *= sc;
            hi16_store_rn(xs, &Khi[r * SB + s * 16]);
        }
        {   // stage V TRANSPOSED (hi-only RN): thread = dim lane, keys w*16..+15
            float xs[16];
#pragma unroll
            for (int u = 0; u < 16; ++u) {
                int trow = stb[ck * 64 + w * 16 + u];     // wave-uniform
                xs[u] = vb[(size_t)trow * DIM + lane];    // coalesced 256B row
            }
            hi16_store_rn(xs, &Vhi[lane * SB + w * 16]);
        }
        __syncthreads();              // K, Vt, tk staged

        // dots: dt = q · K_hi^T  (2-term split: (qH+qL)*kH)
        floatx4 dt[4];
#pragma unroll
        for (int jt = 0; jt < 4; ++jt) dt[jt] = (floatx4){0.f, 0.f, 0.f, 0.f};
#pragma unroll
        for (int kb = 0; kb < 2; ++kb) {
#pragma unroll
            for (int jt = 0; jt < 4; ++jt) {
                short8 bH = *(const short8*)&Khi[(16 * jt + l15) * SB + kb * 32 + quad * 8];
                dt[jt] = __builtin_amdgcn_mfma_f32_16x16x32_bf16(qH[kb], bH, dt[jt], 0, 0, 0);
                dt[jt] = __builtin_amdgcn_mfma_f32_16x16x32_bf16(qL[kb], bH, dt[jt], 0, 0, 0);
            }
        }
        __syncthreads();              // all dots reads of K done -> P may overwrite

        // mask + exp (fp32) + wave-private P-hi write (RN) + denominator partials
#pragma unroll
        for (int jt = 0; jt < 4; ++jt) {
            int tkc = tk[16 * jt + l15];
#pragma unroll
            for (int r = 0; r < 4; ++r) {
                float p = (tqr[r] == tkc) ? 0.f : __expf(dt[jt][r] * 0.125f);
                Dacc[r] += p;
                int idx = (16 * w + quad * 4 + r) * SB + 16 * jt + l15;
                Phi[idx] = (short)((__float_as_uint(p) + 0x8000u) >> 16);
            }
        }

        // PV: O += P_hi·V_hi (A = own P strip -> no barrier; B = Vt hi)
#pragma unroll
        for (int kb = 0; kb < 2; ++kb) {
            short8 aH = *(const short8*)&Phi[(16 * w + l15) * SB + kb * 32 + quad * 8];
#pragma unroll
            for (int a = 0; a < 4; ++a) {
                short8 bH = *(const short8*)&Vhi[(16 * a + l15) * SB + kb * 32 + quad * 8];
                oacc[a] = __builtin_amdgcn_mfma_f32_16x16x32_bf16(aH, bH, oacc[a], 0, 0, 0);
            }
        }
    }

    // epilogue: fused-combine accumulation, token-major (h dimension summed
    // away). Native f32 atomic adds; region is L2-resident (16.8 MB).
#pragma unroll
    for (int r = 0; r < 4; ++r) {
        int t = tqr[r];
        float* po = Onum + (size_t)(b * SEQ + t) * DIM;
#pragma unroll
        for (int a = 0; a < 4; ++a)
            unsafeAtomicAdd(&po[16 * a + l15], oacc[a][r]);
    }
#pragma unroll
    for (int r = 0; r < 4; ++r) {
        float rs = Dacc[r];
        rs += __shfl_xor(rs, 1);
        rs += __shfl_xor(rs, 2);
        rs += __shfl_xor(rs, 4);
        rs += __shfl_xor(rs, 8);
        if (l15 == 0) unsafeAtomicAdd(&Dsum[b * SEQ + tqr[r]], rs);
    }
}

// ---------------------------------------------------------------------------
// Kernel 4: out[b,t,d] = Onum[b,t,d] / Dsum[b,t] -- tiny streaming divide
// (34 MB total vs the old 152 MB Obuf combine).
// ---------------------------------------------------------------------------
__global__ __launch_bounds__(256) void lsh_combine_tok(
    const float* __restrict__ Onum, const float* __restrict__ Dsum,
    float* __restrict__ out)
{
    int gid = blockIdx.x * 256 + threadIdx.x;   // float4 index, 1,048,576 total
    int bt = gid >> 4;
    float invd = 1.0f / Dsum[bt];
    float4 o = ((const float4*)Onum)[gid];
    o.x *= invd; o.y *= invd; o.z *= invd; o.w *= invd;
    ((float4*)out)[gid] = o;
}

extern "C" void kernel_launch(void* const* d_in, const int* in_sizes, int n_in,
                              void* d_out, int out_size, void* d_ws, size_t ws_size,
                              hipStream_t stream)
{
    const float* qk  = (const float*)d_in[0];
    const float* v   = (const float*)d_in[1];
    const float* rot = (const float*)d_in[2];
    float* out = (float*)d_out;

    char* w = (char*)d_ws;
    // workspace layout (21.2 MB):
    //   [0, 2MB)          buckets : int[16*8*4096]
    //   [2, 4MB)          st      : int[16*8*4096]
    //   [4MB, +16.78MB)   Onum    : fp32[16*4096*64]  (token-major numerator)
    //   then              Dsum    : fp32[16*4096]
    int*   buckets = (int*)(w);
    int*   st      = (int*)(w + 2097152);
    float* Onum    = (float*)(w + 4194304);
    float* Dsum    = (float*)(w + 4194304 + 16777216);

    lsh_hash_kernel<<<512, 256, 0, stream>>>(qk, rot, buckets, (float4*)Onum);
    lsh_sort_kernel<<<128, 256, 0, stream>>>(buckets, st);
    lsh_attn_kernel<<<8192, 256, 0, stream>>>(qk, v, st, Onum, Dsum);
    lsh_combine_tok<<<4096, 256, 0, stream>>>(Onum, Dsum, out);
}

// Round 2
// 316.013 us; speedup vs baseline: 1.0961x; 1.0961x over previous
//
#include <hip/hip_runtime.h>
#include <hip/hip_fp16.h>

#define BATCH  16
#define SEQ    4096
#define DIM    64
#define NHASH  8
#define NCHUNK 512   // chunks per batch row (NHASH * SEQ / 64)
#define SB     72    // bf16 LDS row stride: 72*2=144 B, 16B-aligned for b128

typedef __attribute__((ext_vector_type(8))) short short8;   // 8 bf16 (4 VGPR)
typedef __attribute__((ext_vector_type(4))) float floatx4;  // MFMA C/D

__device__ __forceinline__ float trunc_hi(float a) {
    return __uint_as_float(__float_as_uint(a) & 0xffff0000u);
}
__device__ __forceinline__ unsigned pack_hi2(float a, float b) {
    return (__float_as_uint(a) >> 16) | (__float_as_uint(b) & 0xffff0000u);
}
// round-to-nearest bf16 pack: unbiased, max rel err 2^-9 (trunc was 2^-8 + bias)
__device__ __forceinline__ unsigned pack_rn2(float a, float b) {
    unsigned ua = __float_as_uint(a) + 0x8000u;
    unsigned ub = __float_as_uint(b) + 0x8000u;
    return (ua >> 16) | (ub & 0xffff0000u);
}
// 16 fp32 -> 16 bf16 (round-to-nearest) stored as 2x uint4
__device__ __forceinline__ void hi16_store_rn(const float* xs, short* dst) {
    unsigned hd[8];
#pragma unroll
    for (int u = 0; u < 8; ++u) hd[u] = pack_rn2(xs[2*u], xs[2*u + 1]);
    *(uint4*)(dst)     = make_uint4(hd[0], hd[1], hd[2], hd[3]);
    *(uint4*)(dst + 8) = make_uint4(hd[4], hd[5], hd[6], hd[7]);
}
// split 8 fp32 -> bf16 hi/lo short8 fragments in registers (exact split: trunc)
__device__ __forceinline__ void split8_frag(const float* xs, short8* hi, short8* lo) {
    union { unsigned u[4]; short8 s; } H, L;
#pragma unroll
    for (int u = 0; u < 4; ++u) {
        float a = xs[2*u], b = xs[2*u + 1];
        H.u[u] = pack_hi2(a, b);
        L.u[u] = pack_hi2(a - trunc_hi(a), b - trunc_hi(b));
    }
    *hi = H.s; *lo = L.s;
}

// ---------------------------------------------------------------------------
// Kernel 1: LSH hashing (rot slice in LDS, broadcast ds_read + dense fp32 FMA,
// 2 tokens/thread, 2 h'/thread). R11's fused zero-init removed (no atomics).
// ---------------------------------------------------------------------------
__global__ __launch_bounds__(256, 2) void lsh_hash_kernel(
    const float* __restrict__ qk, const float* __restrict__ rot,
    int* __restrict__ buckets)
{
    __shared__ float rs[64 * 128];     // [f][h'][i] = f*128 + h'*32 + i (32 KB)
    int tid = threadIdx.x;
    int tb   = blockIdx.x >> 1;        // 256-token tile
    int hsel = blockIdx.x & 1;         // h half: h = hsel*4 + h'

    {   // stage rot slice: 2048 float4, 8 per thread, coalesced
        const float4* rg = (const float4*)rot;
#pragma unroll
        for (int j = 0; j < 8; ++j) {
            int idx4 = j * 256 + tid;
            int f = idx4 >> 5, r4 = idx4 & 31;
            ((float4*)rs)[idx4] = rg[f * 64 + hsel * 32 + r4];
        }
    }
    __syncthreads();

    int tt = tid & 127;
    int hh = tid >> 7;                 // 0/1, wave-uniform
    int gid0 = tb * 256 + tt;
    int gid1 = gid0 + 128;
    const float* q0 = qk + (size_t)gid0 * DIM;
    const float* q1 = qk + (size_t)gid1 * DIM;

#pragma unroll
    for (int h0 = 0; h0 < 2; ++h0) {
        int hp = hh * 2 + h0;
        const float* rbase = rs + hp * 32;
        float a0[32], a1[32];
#pragma unroll
        for (int i = 0; i < 32; ++i) { a0[i] = 0.f; a1[i] = 0.f; }
#pragma unroll 1
        for (int ft = 0; ft < 8; ++ft) {
            float qa[8], qb[8];
            *(float4*)&qa[0] = *(const float4*)(q0 + ft * 8);
            *(float4*)&qa[4] = *(const float4*)(q0 + ft * 8 + 4);
            *(float4*)&qb[0] = *(const float4*)(q1 + ft * 8);
            *(float4*)&qb[4] = *(const float4*)(q1 + ft * 8 + 4);
#pragma unroll
            for (int f8 = 0; f8 < 8; ++f8) {
                const float* rp = rbase + (ft * 8 + f8) * 128;
                float x = qa[f8], y = qb[f8];
#pragma unroll
                for (int i = 0; i < 32; ++i) {
                    float r = rp[i];
                    a0[i] = fmaf(x, r, a0[i]);
                    a1[i] = fmaf(y, r, a1[i]);
                }
            }
        }
        int h = hsel * 4 + hp;
        {
            float best = a0[0]; int bi = 0;
#pragma unroll
            for (int i = 1; i < 32; ++i) { if (a0[i] > best) { best = a0[i]; bi = i; } }
#pragma unroll
            for (int i = 0; i < 32; ++i) { float nv = -a0[i]; if (nv > best) { best = nv; bi = i + 32; } }
            int b = gid0 >> 12, t = gid0 & 4095;
            buckets[((size_t)b * NHASH + h) * SEQ + t] = bi;
        }
        {
            float best = a1[0]; int bi = 0;
#pragma unroll
            for (int i = 1; i < 32; ++i) { if (a1[i] > best) { best = a1[i]; bi = i; } }
#pragma unroll
            for (int i = 0; i < 32; ++i) { float nv = -a1[i]; if (nv > best) { best = nv; bi = i + 32; } }
            int b = gid1 >> 12, t = gid1 & 4095;
            buckets[((size_t)b * NHASH + h) * SEQ + t] = bi;
        }
    }
}

// ---------------------------------------------------------------------------
// Kernel 2: stable counting sort per (b,h), 4-wave (unchanged).
// ---------------------------------------------------------------------------
__global__ __launch_bounds__(256) void lsh_sort_kernel(
    const int* __restrict__ buckets, int* __restrict__ st)
{
    __shared__ int hist[256 * 65];
    __shared__ int seg[256];
    __shared__ int base[64];

    int bh = blockIdx.x;
    int tid = threadIdx.x;
    int w = tid >> 6, lane = tid & 63;

    for (int i = tid; i < 256 * 65; i += 256) hist[i] = 0;

    int myb[16];
    {
        const int4* bp4 = (const int4*)(buckets + (size_t)bh * SEQ);
#pragma unroll
        for (int u4 = 0; u4 < 4; ++u4) {
            int4 bb = bp4[tid * 4 + u4];
            myb[u4*4+0] = bb.x; myb[u4*4+1] = bb.y;
            myb[u4*4+2] = bb.z; myb[u4*4+3] = bb.w;
        }
    }
    __syncthreads();
    int* hrow = &hist[tid * 65];
#pragma unroll
    for (int u = 0; u < 16; ++u) hrow[myb[u]] += 1;
    __syncthreads();

    {
        int run = 0;
        for (int tp = 0; tp < 64; ++tp) {
            int idx = (w * 64 + tp) * 65 + lane;
            int c0 = hist[idx];
            hist[idx] = run;
            run += c0;
        }
        seg[w * 64 + lane] = run;
    }
    __syncthreads();
    if (tid < 64) {
        int s0 = seg[lane], s1 = seg[64 + lane], s2 = seg[128 + lane], s3 = seg[192 + lane];
        seg[lane] = 0; seg[64 + lane] = s0;
        seg[128 + lane] = s0 + s1; seg[192 + lane] = s0 + s1 + s2;
        int tot = s0 + s1 + s2 + s3;
        int x = tot;
#pragma unroll
        for (int d = 1; d < 64; d <<= 1) {
            int y = __shfl_up(x, d, 64);
            if (lane >= d) x += y;
        }
        base[lane] = x - tot;
    }
    __syncthreads();

    int* op = st + (size_t)bh * SEQ;
#pragma unroll
    for (int u = 0; u < 16; ++u) {
        int bb = myb[u];
        int local = hrow[bb];
        hrow[bb] = local + 1;
        int pos = base[bb] + seg[w * 64 + bb] + local;
        op[pos] = tid * 16 + u;
    }
}

// ---------------------------------------------------------------------------
// Kernel 3: MFMA attention. R12: keep R11's LDS trims (P hi-only RN, no Vlo,
// 18.5 KB -> 8 blocks/CU), REVERT the atomic fused-combine (R11 post-mortem:
// cross-XCD atomic RMW tripled hbm_bytes to 897 MB, attn 107->228 us).
// Epilogue scatters un-normalized O to Obuf in FP16 (rel err 2^-11 -> ~2e-4
// on out after the D-normalized combine) + fp32 Dbuf. Obuf traffic halves
// vs R10: write 67 MB here + read 67 MB in combine.
// ---------------------------------------------------------------------------
__global__ __launch_bounds__(256, 8) void lsh_attn_kernel(
    const float* __restrict__ qk, const float* __restrict__ v,
    const int* __restrict__ st, __half* __restrict__ Obuf, float* __restrict__ Dbuf)
{
    __shared__ short Khi[64 * SB];     // staged K-hi; doubles as P-hi after dots
    __shared__ short Vhi[64 * SB];     // transposed: [dim][key], hi only
    __shared__ int   tk[64];

    short* Phi = Khi;

    int tid  = threadIdx.x;
    int lane = tid & 63;
    int w    = tid >> 6;          // wave id = query-strip / V key-group
    int quad = lane >> 4;
    int l15  = lane & 15;

    int bc = blockIdx.x;
    int b = bc >> 9, c = bc & (NCHUNK - 1);
    int cm = (c + NCHUNK - 1) & (NCHUNK - 1);

    const int*   stb = st + (size_t)b * (NHASH * SEQ);
    const float* qkb = qk + (size_t)b * SEQ * DIM;
    const float* vb  = v  + (size_t)b * SEQ * DIM;

    // ---- Q fragments in registers (both halves use the same Q) ----
    short8 qH[2], qL[2];
    {
        int qt = stb[c * 64 + 16 * w + l15];       // this lane's Q row token
        const float* qp = qkb + (size_t)qt * DIM + 8 * quad;
        float xs[8];
#pragma unroll
        for (int kb = 0; kb < 2; ++kb) {
            *(float4*)&xs[0] = *(const float4*)(qp + 32 * kb);
            *(float4*)&xs[4] = *(const float4*)(qp + 32 * kb + 4);
            split8_frag(xs, &qH[kb], &qL[kb]);
        }
    }
    // mask row-ids for this lane's C-fragment rows (quad*4+r), both halves
    int tqr[4];
#pragma unroll
    for (int r = 0; r < 4; ++r) tqr[r] = stb[c * 64 + 16 * w + quad * 4 + r];

    float   Dacc[4] = {0.f, 0.f, 0.f, 0.f};
    floatx4 oacc[4];
#pragma unroll
    for (int a = 0; a < 4; ++a) oacc[a] = (floatx4){0.f, 0.f, 0.f, 0.f};

    for (int half = 0; half < 2; ++half) {
        int ck = half ? cm : c;
        __syncthreads();              // prev-half P/V LDS reads complete

        {   // stage K (L2-normalized, hi-only RN): 4 threads/row, 16 dims each
            int r = tid >> 2, s = tid & 3;
            int trow = stb[ck * 64 + r];
            if (s == 0) tk[r] = trow;
            const float4* k4 = (const float4*)(qkb + (size_t)trow * DIM + s * 16);
            float xs[16];
            *(float4*)&xs[0]  = k4[0];
            *(float4*)&xs[4]  = k4[1];
            *(float4*)&xs[8]  = k4[2];
            *(float4*)&xs[12] = k4[3];
            float ss = 0.f;
#pragma unroll
            for (int u = 0; u < 16; ++u) ss += xs[u] * xs[u];
            ss += __shfl_xor(ss, 1);
            ss += __shfl_xor(ss, 2);
            float sc = 1.0f / fmaxf(sqrtf(ss), 1e-12f);
#pragma unroll
            for (int u = 0; u < 16; ++u) xs[u] *= sc;
            hi16_store_rn(xs, &Khi[r * SB + s * 16]);
        }
        {   // stage V TRANSPOSED (hi-only RN): thread = dim lane, keys w*16..+15
            float xs[16];
#pragma unroll
            for (int u = 0; u < 16; ++u) {
                int trow = stb[ck * 64 + w * 16 + u];     // wave-uniform
                xs[u] = vb[(size_t)trow * DIM + lane];    // coalesced 256B row
            }
            hi16_store_rn(xs, &Vhi[lane * SB + w * 16]);
        }
        __syncthreads();              // K, Vt, tk staged

        // dots: dt = q · K_hi^T  (2-term split: (qH+qL)*kH)
        floatx4 dt[4];
#pragma unroll
        for (int jt = 0; jt < 4; ++jt) dt[jt] = (floatx4){0.f, 0.f, 0.f, 0.f};
#pragma unroll
        for (int kb = 0; kb < 2; ++kb) {
#pragma unroll
            for (int jt = 0; jt < 4; ++jt) {
                short8 bH = *(const short8*)&Khi[(16 * jt + l15) * SB + kb * 32 + quad * 8];
                dt[jt] = __builtin_amdgcn_mfma_f32_16x16x32_bf16(qH[kb], bH, dt[jt], 0, 0, 0);
                dt[jt] = __builtin_amdgcn_mfma_f32_16x16x32_bf16(qL[kb], bH, dt[jt], 0, 0, 0);
            }
        }
        __syncthreads();              // all dots reads of K done -> P may overwrite

        // mask + exp (fp32) + wave-private P-hi write (RN) + denominator partials
#pragma unroll
        for (int jt = 0; jt < 4; ++jt) {
            int tkc = tk[16 * jt + l15];
#pragma unroll
            for (int r = 0; r < 4; ++r) {
                float p = (tqr[r] == tkc) ? 0.f : __expf(dt[jt][r] * 0.125f);
                Dacc[r] += p;
                int idx = (16 * w + quad * 4 + r) * SB + 16 * jt + l15;
                Phi[idx] = (short)((__float_as_uint(p) + 0x8000u) >> 16);
            }
        }

        // PV: O += P_hi·V_hi (A = own P strip -> no barrier; B = Vt hi)
#pragma unroll
        for (int kb = 0; kb < 2; ++kb) {
            short8 aH = *(const short8*)&Phi[(16 * w + l15) * SB + kb * 32 + quad * 8];
#pragma unroll
            for (int a = 0; a < 4; ++a) {
                short8 bH = *(const short8*)&Vhi[(16 * a + l15) * SB + kb * 32 + quad * 8];
                oacc[a] = __builtin_amdgcn_mfma_f32_16x16x32_bf16(aH, bH, oacc[a], 0, 0, 0);
            }
        }
    }

    // epilogue: scatter to token-major rows Obuf[((b*4096+t)*8 + h)*64 + d]
    // in fp16 (halved round-trip), h = c>>6.
    int h = c >> 6;
#pragma unroll
    for (int r = 0; r < 4; ++r) {
        int t = tqr[r];
        size_t rowb = ((size_t)(b * SEQ + t) * NHASH + h) * DIM;
#pragma unroll
        for (int a = 0; a < 4; ++a)
            Obuf[rowb + 16 * a + l15] = __float2half(oacc[a][r]);
    }
#pragma unroll
    for (int r = 0; r < 4; ++r) {
        float rs = Dacc[r];
        rs += __shfl_xor(rs, 1);
        rs += __shfl_xor(rs, 2);
        rs += __shfl_xor(rs, 4);
        rs += __shfl_xor(rs, 8);
        if (l15 == 0) Dbuf[(size_t)(b * SEQ + tqr[r]) * NHASH + h] = rs;
    }
}

// ---------------------------------------------------------------------------
// Kernel 4: out[b,t] = sum_h O_h / sum_h D_h -- streaming, fp16 numerator.
// Traffic: read 67 MB (Obuf) + 2 MB (Dbuf), write 16.8 MB.
// ---------------------------------------------------------------------------
__global__ __launch_bounds__(256) void lsh_combine_tok(
    const __half* __restrict__ Obuf, const float* __restrict__ Dbuf,
    float* __restrict__ out)
{
    int gid = blockIdx.x * 256 + threadIdx.x;   // (b*4096+t)*16 + d4
    int d4 = gid & 15;
    int bt = gid >> 4;

    const __half* op = Obuf + (size_t)bt * (NHASH * DIM) + d4 * 4;
    const float*  dp = Dbuf + (size_t)bt * NHASH;

    float4 n = make_float4(0.f, 0.f, 0.f, 0.f);
    float den = 0.f;
#pragma unroll
    for (int h = 0; h < NHASH; ++h) {
        uint2 u = *(const uint2*)(op + h * DIM);
        __half2 p01 = *(__half2*)&u.x;
        __half2 p23 = *(__half2*)&u.y;
        float2 f01 = __half22float2(p01);
        float2 f23 = __half22float2(p23);
        den += dp[h];
        n.x += f01.x; n.y += f01.y; n.z += f23.x; n.w += f23.y;
    }
    float invd = 1.0f / den;
    float4 r; r.x = n.x*invd; r.y = n.y*invd; r.z = n.z*invd; r.w = n.w*invd;
    ((float4*)out)[gid] = r;
}

extern "C" void kernel_launch(void* const* d_in, const int* in_sizes, int n_in,
                              void* d_out, int out_size, void* d_ws, size_t ws_size,
                              hipStream_t stream)
{
    const float* qk  = (const float*)d_in[0];
    const float* v   = (const float*)d_in[1];
    const float* rot = (const float*)d_in[2];
    float* out = (float*)d_out;

    char* w = (char*)d_ws;
    // workspace layout (73.2 MB):
    //   [0, 2MB)          buckets : int[16*8*4096]
    //   [2, 4MB)          st      : int[16*8*4096]
    //   [4MB, +67.1MB)    Obuf    : fp16[16*4096*8*64]  (token-major, h inner)
    //   then              Dbuf    : fp32[16*4096*8]
    int*    buckets = (int*)(w);
    int*    st      = (int*)(w + 2097152);
    __half* Obuf    = (__half*)(w + 4194304);
    float*  Dbuf    = (float*)(w + 4194304 + 67108864);

    lsh_hash_kernel<<<512, 256, 0, stream>>>(qk, rot, buckets);
    lsh_sort_kernel<<<128, 256, 0, stream>>>(buckets, st);
    lsh_attn_kernel<<<8192, 256, 0, stream>>>(qk, v, st, Obuf, Dbuf);
    lsh_combine_tok<<<4096, 256, 0, stream>>>(Obuf, Dbuf, out);
}

// Round 3
// 311.448 us; speedup vs baseline: 1.1122x; 1.0147x over previous
//
#include <hip/hip_runtime.h>
#include <hip/hip_fp16.h>

#define BATCH  16
#define SEQ    4096
#define DIM    64
#define NHASH  8
#define NCHUNK 512   // chunks per batch row (NHASH * SEQ / 64)
#define SB     72    // bf16 LDS row stride: 72*2=144 B, 16B-aligned for b128

typedef __attribute__((ext_vector_type(8))) short short8;   // 8 bf16 (4 VGPR)
typedef __attribute__((ext_vector_type(4))) float floatx4;  // MFMA C/D

__device__ __forceinline__ float trunc_hi(float a) {
    return __uint_as_float(__float_as_uint(a) & 0xffff0000u);
}
__device__ __forceinline__ unsigned pack_hi2(float a, float b) {
    return (__float_as_uint(a) >> 16) | (__float_as_uint(b) & 0xffff0000u);
}
// round-to-nearest bf16 pack: unbiased, max rel err 2^-9
__device__ __forceinline__ unsigned pack_rn2(float a, float b) {
    unsigned ua = __float_as_uint(a) + 0x8000u;
    unsigned ub = __float_as_uint(b) + 0x8000u;
    return (ua >> 16) | (ub & 0xffff0000u);
}
// 16 fp32 -> 16 bf16 (round-to-nearest) stored as 2x uint4
__device__ __forceinline__ void hi16_store_rn(const float* xs, short* dst) {
    unsigned hd[8];
#pragma unroll
    for (int u = 0; u < 8; ++u) hd[u] = pack_rn2(xs[2*u], xs[2*u + 1]);
    *(uint4*)(dst)     = make_uint4(hd[0], hd[1], hd[2], hd[3]);
    *(uint4*)(dst + 8) = make_uint4(hd[4], hd[5], hd[6], hd[7]);
}
// split 8 fp32 -> bf16 hi/lo short8 fragments in registers (exact split: trunc)
__device__ __forceinline__ void split8_frag(const float* xs, short8* hi, short8* lo) {
    union { unsigned u[4]; short8 s; } H, L;
#pragma unroll
    for (int u = 0; u < 4; ++u) {
        float a = xs[2*u], b = xs[2*u + 1];
        H.u[u] = pack_hi2(a, b);
        L.u[u] = pack_hi2(a - trunc_hi(a), b - trunc_hi(b));
    }
    *hi = H.s; *lo = L.s;
}

// ---------------------------------------------------------------------------
// Kernel 1: LSH hashing (rot slice in LDS, broadcast ds_read + dense fp32 FMA,
// 2 tokens/thread, 2 h'/thread). Unchanged.
// ---------------------------------------------------------------------------
__global__ __launch_bounds__(256, 2) void lsh_hash_kernel(
    const float* __restrict__ qk, const float* __restrict__ rot,
    int* __restrict__ buckets)
{
    __shared__ float rs[64 * 128];     // [f][h'][i] = f*128 + h'*32 + i (32 KB)
    int tid = threadIdx.x;
    int tb   = blockIdx.x >> 1;        // 256-token tile
    int hsel = blockIdx.x & 1;         // h half: h = hsel*4 + h'

    {   // stage rot slice: 2048 float4, 8 per thread, coalesced
        const float4* rg = (const float4*)rot;
#pragma unroll
        for (int j = 0; j < 8; ++j) {
            int idx4 = j * 256 + tid;
            int f = idx4 >> 5, r4 = idx4 & 31;
            ((float4*)rs)[idx4] = rg[f * 64 + hsel * 32 + r4];
        }
    }
    __syncthreads();

    int tt = tid & 127;
    int hh = tid >> 7;                 // 0/1, wave-uniform
    int gid0 = tb * 256 + tt;
    int gid1 = gid0 + 128;
    const float* q0 = qk + (size_t)gid0 * DIM;
    const float* q1 = qk + (size_t)gid1 * DIM;

#pragma unroll
    for (int h0 = 0; h0 < 2; ++h0) {
        int hp = hh * 2 + h0;
        const float* rbase = rs + hp * 32;
        float a0[32], a1[32];
#pragma unroll
        for (int i = 0; i < 32; ++i) { a0[i] = 0.f; a1[i] = 0.f; }
#pragma unroll 1
        for (int ft = 0; ft < 8; ++ft) {
            float qa[8], qb[8];
            *(float4*)&qa[0] = *(const float4*)(q0 + ft * 8);
            *(float4*)&qa[4] = *(const float4*)(q0 + ft * 8 + 4);
            *(float4*)&qb[0] = *(const float4*)(q1 + ft * 8);
            *(float4*)&qb[4] = *(const float4*)(q1 + ft * 8 + 4);
#pragma unroll
            for (int f8 = 0; f8 < 8; ++f8) {
                const float* rp = rbase + (ft * 8 + f8) * 128;
                float x = qa[f8], y = qb[f8];
#pragma unroll
                for (int i = 0; i < 32; ++i) {
                    float r = rp[i];
                    a0[i] = fmaf(x, r, a0[i]);
                    a1[i] = fmaf(y, r, a1[i]);
                }
            }
        }
        int h = hsel * 4 + hp;
        {
            float best = a0[0]; int bi = 0;
#pragma unroll
            for (int i = 1; i < 32; ++i) { if (a0[i] > best) { best = a0[i]; bi = i; } }
#pragma unroll
            for (int i = 0; i < 32; ++i) { float nv = -a0[i]; if (nv > best) { best = nv; bi = i + 32; } }
            int b = gid0 >> 12, t = gid0 & 4095;
            buckets[((size_t)b * NHASH + h) * SEQ + t] = bi;
        }
        {
            float best = a1[0]; int bi = 0;
#pragma unroll
            for (int i = 1; i < 32; ++i) { if (a1[i] > best) { best = a1[i]; bi = i; } }
#pragma unroll
            for (int i = 0; i < 32; ++i) { float nv = -a1[i]; if (nv > best) { best = nv; bi = i + 32; } }
            int b = gid1 >> 12, t = gid1 & 4095;
            buckets[((size_t)b * NHASH + h) * SEQ + t] = bi;
        }
    }
}

// ---------------------------------------------------------------------------
// Kernel 2: stable counting sort per (b,h), 4-wave (unchanged).
// ---------------------------------------------------------------------------
__global__ __launch_bounds__(256) void lsh_sort_kernel(
    const int* __restrict__ buckets, int* __restrict__ st)
{
    __shared__ int hist[256 * 65];
    __shared__ int seg[256];
    __shared__ int base[64];

    int bh = blockIdx.x;
    int tid = threadIdx.x;
    int w = tid >> 6, lane = tid & 63;

    for (int i = tid; i < 256 * 65; i += 256) hist[i] = 0;

    int myb[16];
    {
        const int4* bp4 = (const int4*)(buckets + (size_t)bh * SEQ);
#pragma unroll
        for (int u4 = 0; u4 < 4; ++u4) {
            int4 bb = bp4[tid * 4 + u4];
            myb[u4*4+0] = bb.x; myb[u4*4+1] = bb.y;
            myb[u4*4+2] = bb.z; myb[u4*4+3] = bb.w;
        }
    }
    __syncthreads();
    int* hrow = &hist[tid * 65];
#pragma unroll
    for (int u = 0; u < 16; ++u) hrow[myb[u]] += 1;
    __syncthreads();

    {
        int run = 0;
        for (int tp = 0; tp < 64; ++tp) {
            int idx = (w * 64 + tp) * 65 + lane;
            int c0 = hist[idx];
            hist[idx] = run;
            run += c0;
        }
        seg[w * 64 + lane] = run;
    }
    __syncthreads();
    if (tid < 64) {
        int s0 = seg[lane], s1 = seg[64 + lane], s2 = seg[128 + lane], s3 = seg[192 + lane];
        seg[lane] = 0; seg[64 + lane] = s0;
        seg[128 + lane] = s0 + s1; seg[192 + lane] = s0 + s1 + s2;
        int tot = s0 + s1 + s2 + s3;
        int x = tot;
#pragma unroll
        for (int d = 1; d < 64; d <<= 1) {
            int y = __shfl_up(x, d, 64);
            if (lane >= d) x += y;
        }
        base[lane] = x - tot;
    }
    __syncthreads();

    int* op = st + (size_t)bh * SEQ;
#pragma unroll
    for (int u = 0; u < 16; ++u) {
        int bb = myb[u];
        int local = hrow[bb];
        hrow[bb] = local + 1;
        int pos = base[bb] + seg[w * 64 + bb] + local;
        op[pos] = tid * 16 + u;
    }
}

// ---------------------------------------------------------------------------
// Kernel 3: MFMA attention. R13: keep R12's LDS trims (P hi-only RN, 18.5 KB,
// 8 blocks/CU) + fp16 Obuf, ADD XCD-aware chunk assignment.
// R12 post-mortem: 8 blocks/CU widened the resident blockIdx window to ~4
// batches = 8 MB gather working set per 4 MB XCD-L2 -> hit rate collapsed
// (FETCH 157->481 MB, attn 107->190 us). Fix: bc = (blockIdx&7)*1024 +
// (blockIdx>>3). Consecutive blockIdx round-robin XCDs, so XCD x processes
// chunks [x*1024, x*1024+1024) = 2 whole batches sequentially -- per-XCD
// working set 2 MB (one batch) fits L2 entirely. Bijective (8192 = 8*1024).
// ---------------------------------------------------------------------------
__global__ __launch_bounds__(256, 8) void lsh_attn_kernel(
    const float* __restrict__ qk, const float* __restrict__ v,
    const int* __restrict__ st, __half* __restrict__ Obuf, float* __restrict__ Dbuf)
{
    __shared__ short Khi[64 * SB];     // staged K-hi; doubles as P-hi after dots
    __shared__ short Vhi[64 * SB];     // transposed: [dim][key], hi only
    __shared__ int   tk[64];

    short* Phi = Khi;

    int tid  = threadIdx.x;
    int lane = tid & 63;
    int w    = tid >> 6;          // wave id = query-strip / V key-group
    int quad = lane >> 4;
    int l15  = lane & 15;

    // XCD-aware chunk assignment (see header comment)
    int B  = blockIdx.x;
    int bc = ((B & 7) << 10) | (B >> 3);
    int b = bc >> 9, c = bc & (NCHUNK - 1);
    int cm = (c + NCHUNK - 1) & (NCHUNK - 1);

    const int*   stb = st + (size_t)b * (NHASH * SEQ);
    const float* qkb = qk + (size_t)b * SEQ * DIM;
    const float* vb  = v  + (size_t)b * SEQ * DIM;

    // ---- Q fragments in registers (both halves use the same Q) ----
    short8 qH[2], qL[2];
    {
        int qt = stb[c * 64 + 16 * w + l15];       // this lane's Q row token
        const float* qp = qkb + (size_t)qt * DIM + 8 * quad;
        float xs[8];
#pragma unroll
        for (int kb = 0; kb < 2; ++kb) {
            *(float4*)&xs[0] = *(const float4*)(qp + 32 * kb);
            *(float4*)&xs[4] = *(const float4*)(qp + 32 * kb + 4);
            split8_frag(xs, &qH[kb], &qL[kb]);
        }
    }
    // mask row-ids for this lane's C-fragment rows (quad*4+r), both halves
    int tqr[4];
#pragma unroll
    for (int r = 0; r < 4; ++r) tqr[r] = stb[c * 64 + 16 * w + quad * 4 + r];

    float   Dacc[4] = {0.f, 0.f, 0.f, 0.f};
    floatx4 oacc[4];
#pragma unroll
    for (int a = 0; a < 4; ++a) oacc[a] = (floatx4){0.f, 0.f, 0.f, 0.f};

    for (int half = 0; half < 2; ++half) {
        int ck = half ? cm : c;
        __syncthreads();              // prev-half P/V LDS reads complete

        {   // stage K (L2-normalized, hi-only RN): 4 threads/row, 16 dims each
            int r = tid >> 2, s = tid & 3;
            int trow = stb[ck * 64 + r];
            if (s == 0) tk[r] = trow;
            const float4* k4 = (const float4*)(qkb + (size_t)trow * DIM + s * 16);
            float xs[16];
            *(float4*)&xs[0]  = k4[0];
            *(float4*)&xs[4]  = k4[1];
            *(float4*)&xs[8]  = k4[2];
            *(float4*)&xs[12] = k4[3];
            float ss = 0.f;
#pragma unroll
            for (int u = 0; u < 16; ++u) ss += xs[u] * xs[u];
            ss += __shfl_xor(ss, 1);
            ss += __shfl_xor(ss, 2);
            float sc = 1.0f / fmaxf(sqrtf(ss), 1e-12f);
#pragma unroll
            for (int u = 0; u < 16; ++u) xs[u] *= sc;
            hi16_store_rn(xs, &Khi[r * SB + s * 16]);
        }
        {   // stage V TRANSPOSED (hi-only RN): thread = dim lane, keys w*16..+15
            float xs[16];
#pragma unroll
            for (int u = 0; u < 16; ++u) {
                int trow = stb[ck * 64 + w * 16 + u];     // wave-uniform
                xs[u] = vb[(size_t)trow * DIM + lane];    // coalesced 256B row
            }
            hi16_store_rn(xs, &Vhi[lane * SB + w * 16]);
        }
        __syncthreads();              // K, Vt, tk staged

        // dots: dt = q · K_hi^T  (2-term split: (qH+qL)*kH)
        floatx4 dt[4];
#pragma unroll
        for (int jt = 0; jt < 4; ++jt) dt[jt] = (floatx4){0.f, 0.f, 0.f, 0.f};
#pragma unroll
        for (int kb = 0; kb < 2; ++kb) {
#pragma unroll
            for (int jt = 0; jt < 4; ++jt) {
                short8 bH = *(const short8*)&Khi[(16 * jt + l15) * SB + kb * 32 + quad * 8];
                dt[jt] = __builtin_amdgcn_mfma_f32_16x16x32_bf16(qH[kb], bH, dt[jt], 0, 0, 0);
                dt[jt] = __builtin_amdgcn_mfma_f32_16x16x32_bf16(qL[kb], bH, dt[jt], 0, 0, 0);
            }
        }
        __syncthreads();              // all dots reads of K done -> P may overwrite

        // mask + exp (fp32) + wave-private P-hi write (RN) + denominator partials
#pragma unroll
        for (int jt = 0; jt < 4; ++jt) {
            int tkc = tk[16 * jt + l15];
#pragma unroll
            for (int r = 0; r < 4; ++r) {
                float p = (tqr[r] == tkc) ? 0.f : __expf(dt[jt][r] * 0.125f);
                Dacc[r] += p;
                int idx = (16 * w + quad * 4 + r) * SB + 16 * jt + l15;
                Phi[idx] = (short)((__float_as_uint(p) + 0x8000u) >> 16);
            }
        }

        // PV: O += P_hi·V_hi (A = own P strip -> no barrier; B = Vt hi)
#pragma unroll
        for (int kb = 0; kb < 2; ++kb) {
            short8 aH = *(const short8*)&Phi[(16 * w + l15) * SB + kb * 32 + quad * 8];
#pragma unroll
            for (int a = 0; a < 4; ++a) {
                short8 bH = *(const short8*)&Vhi[(16 * a + l15) * SB + kb * 32 + quad * 8];
                oacc[a] = __builtin_amdgcn_mfma_f32_16x16x32_bf16(aH, bH, oacc[a], 0, 0, 0);
            }
        }
    }

    // epilogue: scatter to token-major rows Obuf[((b*4096+t)*8 + h)*64 + d]
    // in fp16 (halved round-trip), h = c>>6.
    int h = c >> 6;
#pragma unroll
    for (int r = 0; r < 4; ++r) {
        int t = tqr[r];
        size_t rowb = ((size_t)(b * SEQ + t) * NHASH + h) * DIM;
#pragma unroll
        for (int a = 0; a < 4; ++a)
            Obuf[rowb + 16 * a + l15] = __float2half(oacc[a][r]);
    }
#pragma unroll
    for (int r = 0; r < 4; ++r) {
        float rs = Dacc[r];
        rs += __shfl_xor(rs, 1);
        rs += __shfl_xor(rs, 2);
        rs += __shfl_xor(rs, 4);
        rs += __shfl_xor(rs, 8);
        if (l15 == 0) Dbuf[(size_t)(b * SEQ + tqr[r]) * NHASH + h] = rs;
    }
}

// ---------------------------------------------------------------------------
// Kernel 4: out[b,t] = sum_h O_h / sum_h D_h -- streaming, fp16 numerator.
// Traffic: read 67 MB (Obuf) + 2 MB (Dbuf), write 16.8 MB.
// ---------------------------------------------------------------------------
__global__ __launch_bounds__(256) void lsh_combine_tok(
    const __half* __restrict__ Obuf, const float* __restrict__ Dbuf,
    float* __restrict__ out)
{
    int gid = blockIdx.x * 256 + threadIdx.x;   // (b*4096+t)*16 + d4
    int d4 = gid & 15;
    int bt = gid >> 4;

    const __half* op = Obuf + (size_t)bt * (NHASH * DIM) + d4 * 4;
    const float*  dp = Dbuf + (size_t)bt * NHASH;

    float4 n = make_float4(0.f, 0.f, 0.f, 0.f);
    float den = 0.f;
#pragma unroll
    for (int h = 0; h < NHASH; ++h) {
        uint2 u = *(const uint2*)(op + h * DIM);
        __half2 p01 = *(__half2*)&u.x;
        __half2 p23 = *(__half2*)&u.y;
        float2 f01 = __half22float2(p01);
        float2 f23 = __half22float2(p23);
        den += dp[h];
        n.x += f01.x; n.y += f01.y; n.z += f23.x; n.w += f23.y;
    }
    float invd = 1.0f / den;
    float4 r; r.x = n.x*invd; r.y = n.y*invd; r.z = n.z*invd; r.w = n.w*invd;
    ((float4*)out)[gid] = r;
}

extern "C" void kernel_launch(void* const* d_in, const int* in_sizes, int n_in,
                              void* d_out, int out_size, void* d_ws, size_t ws_size,
                              hipStream_t stream)
{
    const float* qk  = (const float*)d_in[0];
    const float* v   = (const float*)d_in[1];
    const float* rot = (const float*)d_in[2];
    float* out = (float*)d_out;

    char* w = (char*)d_ws;
    // workspace layout (73.2 MB):
    //   [0, 2MB)          buckets : int[16*8*4096]
    //   [2, 4MB)          st      : int[16*8*4096]
    //   [4MB, +67.1MB)    Obuf    : fp16[16*4096*8*64]  (token-major, h inner)
    //   then              Dbuf    : fp32[16*4096*8]
    int*    buckets = (int*)(w);
    int*    st      = (int*)(w + 2097152);
    __half* Obuf    = (__half*)(w + 4194304);
    float*  Dbuf    = (float*)(w + 4194304 + 67108864);

    lsh_hash_kernel<<<512, 256, 0, stream>>>(qk, rot, buckets);
    lsh_sort_kernel<<<128, 256, 0, stream>>>(buckets, st);
    lsh_attn_kernel<<<8192, 256, 0, stream>>>(qk, v, st, Obuf, Dbuf);
    lsh_combine_tok<<<4096, 256, 0, stream>>>(Obuf, Dbuf, out);
}

// Round 4
// 200.782 us; speedup vs baseline: 1.7252x; 1.5512x over previous
//
#include <hip/hip_runtime.h>
#include <hip/hip_fp16.h>

#define BATCH  16
#define SEQ    4096
#define DIM    64
#define NHASH  8
#define NCHUNK 512   // chunks per batch row (NHASH * SEQ / 64)
#define SB     72    // bf16 LDS row stride: 72*2=144 B, 16B-aligned for b128

typedef __attribute__((ext_vector_type(8))) short short8;   // 8 bf16 (4 VGPR)
typedef __attribute__((ext_vector_type(4))) float floatx4;  // MFMA C/D

__device__ __forceinline__ float trunc_hi(float a) {
    return __uint_as_float(__float_as_uint(a) & 0xffff0000u);
}
__device__ __forceinline__ unsigned pack_hi2(float a, float b) {
    return (__float_as_uint(a) >> 16) | (__float_as_uint(b) & 0xffff0000u);
}
// round-to-nearest bf16 pack: unbiased, max rel err 2^-9
__device__ __forceinline__ unsigned pack_rn2(float a, float b) {
    unsigned ua = __float_as_uint(a) + 0x8000u;
    unsigned ub = __float_as_uint(b) + 0x8000u;
    return (ua >> 16) | (ub & 0xffff0000u);
}
// 16 fp32 -> 16 bf16 (round-to-nearest) stored as 2x uint4
__device__ __forceinline__ void hi16_store_rn(const float* xs, short* dst) {
    unsigned hd[8];
#pragma unroll
    for (int u = 0; u < 8; ++u) hd[u] = pack_rn2(xs[2*u], xs[2*u + 1]);
    *(uint4*)(dst)     = make_uint4(hd[0], hd[1], hd[2], hd[3]);
    *(uint4*)(dst + 8) = make_uint4(hd[4], hd[5], hd[6], hd[7]);
}
// split 8 fp32 -> bf16 hi/lo short8 fragments in registers (exact split: trunc)
__device__ __forceinline__ void split8_frag(const float* xs, short8* hi, short8* lo) {
    union { unsigned u[4]; short8 s; } H, L;
#pragma unroll
    for (int u = 0; u < 4; ++u) {
        float a = xs[2*u], b = xs[2*u + 1];
        H.u[u] = pack_hi2(a, b);
        L.u[u] = pack_hi2(a - trunc_hi(a), b - trunc_hi(b));
    }
    *hi = H.s; *lo = L.s;
}

// ---------------------------------------------------------------------------
// Kernel 1: LSH hashing (rot slice in LDS, broadcast ds_read + dense fp32 FMA,
// 2 tokens/thread, 2 h'/thread). Unchanged.
// ---------------------------------------------------------------------------
__global__ __launch_bounds__(256, 2) void lsh_hash_kernel(
    const float* __restrict__ qk, const float* __restrict__ rot,
    int* __restrict__ buckets)
{
    __shared__ float rs[64 * 128];     // [f][h'][i] = f*128 + h'*32 + i (32 KB)
    int tid = threadIdx.x;
    int tb   = blockIdx.x >> 1;        // 256-token tile
    int hsel = blockIdx.x & 1;         // h half: h = hsel*4 + h'

    {   // stage rot slice: 2048 float4, 8 per thread, coalesced
        const float4* rg = (const float4*)rot;
#pragma unroll
        for (int j = 0; j < 8; ++j) {
            int idx4 = j * 256 + tid;
            int f = idx4 >> 5, r4 = idx4 & 31;
            ((float4*)rs)[idx4] = rg[f * 64 + hsel * 32 + r4];
        }
    }
    __syncthreads();

    int tt = tid & 127;
    int hh = tid >> 7;                 // 0/1, wave-uniform
    int gid0 = tb * 256 + tt;
    int gid1 = gid0 + 128;
    const float* q0 = qk + (size_t)gid0 * DIM;
    const float* q1 = qk + (size_t)gid1 * DIM;

#pragma unroll
    for (int h0 = 0; h0 < 2; ++h0) {
        int hp = hh * 2 + h0;
        const float* rbase = rs + hp * 32;
        float a0[32], a1[32];
#pragma unroll
        for (int i = 0; i < 32; ++i) { a0[i] = 0.f; a1[i] = 0.f; }
#pragma unroll 1
        for (int ft = 0; ft < 8; ++ft) {
            float qa[8], qb[8];
            *(float4*)&qa[0] = *(const float4*)(q0 + ft * 8);
            *(float4*)&qa[4] = *(const float4*)(q0 + ft * 8 + 4);
            *(float4*)&qb[0] = *(const float4*)(q1 + ft * 8);
            *(float4*)&qb[4] = *(const float4*)(q1 + ft * 8 + 4);
#pragma unroll
            for (int f8 = 0; f8 < 8; ++f8) {
                const float* rp = rbase + (ft * 8 + f8) * 128;
                float x = qa[f8], y = qb[f8];
#pragma unroll
                for (int i = 0; i < 32; ++i) {
                    float r = rp[i];
                    a0[i] = fmaf(x, r, a0[i]);
                    a1[i] = fmaf(y, r, a1[i]);
                }
            }
        }
        int h = hsel * 4 + hp;
        {
            float best = a0[0]; int bi = 0;
#pragma unroll
            for (int i = 1; i < 32; ++i) { if (a0[i] > best) { best = a0[i]; bi = i; } }
#pragma unroll
            for (int i = 0; i < 32; ++i) { float nv = -a0[i]; if (nv > best) { best = nv; bi = i + 32; } }
            int b = gid0 >> 12, t = gid0 & 4095;
            buckets[((size_t)b * NHASH + h) * SEQ + t] = bi;
        }
        {
            float best = a1[0]; int bi = 0;
#pragma unroll
            for (int i = 1; i < 32; ++i) { if (a1[i] > best) { best = a1[i]; bi = i; } }
#pragma unroll
            for (int i = 0; i < 32; ++i) { float nv = -a1[i]; if (nv > best) { best = nv; bi = i + 32; } }
            int b = gid1 >> 12, t = gid1 & 4095;
            buckets[((size_t)b * NHASH + h) * SEQ + t] = bi;
        }
    }
}

// ---------------------------------------------------------------------------
// Kernel 2: stable counting sort per (b,h), 4-wave (unchanged).
// ---------------------------------------------------------------------------
__global__ __launch_bounds__(256) void lsh_sort_kernel(
    const int* __restrict__ buckets, int* __restrict__ st)
{
    __shared__ int hist[256 * 65];
    __shared__ int seg[256];
    __shared__ int base[64];

    int bh = blockIdx.x;
    int tid = threadIdx.x;
    int w = tid >> 6, lane = tid & 63;

    for (int i = tid; i < 256 * 65; i += 256) hist[i] = 0;

    int myb[16];
    {
        const int4* bp4 = (const int4*)(buckets + (size_t)bh * SEQ);
#pragma unroll
        for (int u4 = 0; u4 < 4; ++u4) {
            int4 bb = bp4[tid * 4 + u4];
            myb[u4*4+0] = bb.x; myb[u4*4+1] = bb.y;
            myb[u4*4+2] = bb.z; myb[u4*4+3] = bb.w;
        }
    }
    __syncthreads();
    int* hrow = &hist[tid * 65];
#pragma unroll
    for (int u = 0; u < 16; ++u) hrow[myb[u]] += 1;
    __syncthreads();

    {
        int run = 0;
        for (int tp = 0; tp < 64; ++tp) {
            int idx = (w * 64 + tp) * 65 + lane;
            int c0 = hist[idx];
            hist[idx] = run;
            run += c0;
        }
        seg[w * 64 + lane] = run;
    }
    __syncthreads();
    if (tid < 64) {
        int s0 = seg[lane], s1 = seg[64 + lane], s2 = seg[128 + lane], s3 = seg[192 + lane];
        seg[lane] = 0; seg[64 + lane] = s0;
        seg[128 + lane] = s0 + s1; seg[192 + lane] = s0 + s1 + s2;
        int tot = s0 + s1 + s2 + s3;
        int x = tot;
#pragma unroll
        for (int d = 1; d < 64; d <<= 1) {
            int y = __shfl_up(x, d, 64);
            if (lane >= d) x += y;
        }
        base[lane] = x - tot;
    }
    __syncthreads();

    int* op = st + (size_t)bh * SEQ;
#pragma unroll
    for (int u = 0; u < 16; ++u) {
        int bb = myb[u];
        int local = hrow[bb];
        hrow[bb] = local + 1;
        int pos = base[bb] + seg[w * 64 + bb] + local;
        op[pos] = tid * 16 + u;
    }
}

// ---------------------------------------------------------------------------
// Kernel 3: MFMA attention. R14: single-variable test -- occupancy capped
// back to 5 blocks/CU (R10's level) via a 10 KB LDS pad, keeping all R12/R13
// gains (P hi-only RN -> 40 LDS ops/half, fp16 Obuf, XCD swizzle).
// Evidence: R10(5blk)=157MB FETCH/107us; R11/R12/R13(8blk)=404-481MB FETCH/
// 184-228us across three different epilogues -- occupancy is the common
// factor for the gather-hit-rate collapse (resident dirty Obuf lines + 2MB
// batch working set exceed 4MB XCD-L2 at 8 blk/CU).
// ---------------------------------------------------------------------------
__global__ __launch_bounds__(256, 5) void lsh_attn_kernel(
    const float* __restrict__ qk, const float* __restrict__ v,
    const int* __restrict__ st, __half* __restrict__ Obuf, float* __restrict__ Dbuf)
{
    __shared__ short Khi[64 * SB];     // staged K-hi; doubles as P-hi after dots
    __shared__ short Vhi[64 * SB];     // transposed: [dim][key], hi only
    __shared__ int   tk[64];
    __shared__ float lds_pad[2560];    // 10 KB occupancy cap: 29.2 KB -> 5 blk/CU

    short* Phi = Khi;

    int tid  = threadIdx.x;
    {   // volatile touch so the pad allocation can't be eliminated
        volatile float* vp = lds_pad;
        vp[tid] = 0.f;
    }
    int lane = tid & 63;
    int w    = tid >> 6;          // wave id = query-strip / V key-group
    int quad = lane >> 4;
    int l15  = lane & 15;

    // XCD-aware chunk assignment: XCD x processes chunks [x*1024, x*1024+1024)
    // = 2 whole batches sequentially (8192 = 8 XCDs * 1024, bijective).
    int B  = blockIdx.x;
    int bc = ((B & 7) << 10) | (B >> 3);
    int b = bc >> 9, c = bc & (NCHUNK - 1);
    int cm = (c + NCHUNK - 1) & (NCHUNK - 1);

    const int*   stb = st + (size_t)b * (NHASH * SEQ);
    const float* qkb = qk + (size_t)b * SEQ * DIM;
    const float* vb  = v  + (size_t)b * SEQ * DIM;

    // ---- Q fragments in registers (both halves use the same Q) ----
    short8 qH[2], qL[2];
    {
        int qt = stb[c * 64 + 16 * w + l15];       // this lane's Q row token
        const float* qp = qkb + (size_t)qt * DIM + 8 * quad;
        float xs[8];
#pragma unroll
        for (int kb = 0; kb < 2; ++kb) {
            *(float4*)&xs[0] = *(const float4*)(qp + 32 * kb);
            *(float4*)&xs[4] = *(const float4*)(qp + 32 * kb + 4);
            split8_frag(xs, &qH[kb], &qL[kb]);
        }
    }
    // mask row-ids for this lane's C-fragment rows (quad*4+r), both halves
    int tqr[4];
#pragma unroll
    for (int r = 0; r < 4; ++r) tqr[r] = stb[c * 64 + 16 * w + quad * 4 + r];

    float   Dacc[4] = {0.f, 0.f, 0.f, 0.f};
    floatx4 oacc[4];
#pragma unroll
    for (int a = 0; a < 4; ++a) oacc[a] = (floatx4){0.f, 0.f, 0.f, 0.f};

    for (int half = 0; half < 2; ++half) {
        int ck = half ? cm : c;
        __syncthreads();              // prev-half P/V LDS reads complete

        {   // stage K (L2-normalized, hi-only RN): 4 threads/row, 16 dims each
            int r = tid >> 2, s = tid & 3;
            int trow = stb[ck * 64 + r];
            if (s == 0) tk[r] = trow;
            const float4* k4 = (const float4*)(qkb + (size_t)trow * DIM + s * 16);
            float xs[16];
            *(float4*)&xs[0]  = k4[0];
            *(float4*)&xs[4]  = k4[1];
            *(float4*)&xs[8]  = k4[2];
            *(float4*)&xs[12] = k4[3];
            float ss = 0.f;
#pragma unroll
            for (int u = 0; u < 16; ++u) ss += xs[u] * xs[u];
            ss += __shfl_xor(ss, 1);
            ss += __shfl_xor(ss, 2);
            float sc = 1.0f / fmaxf(sqrtf(ss), 1e-12f);
#pragma unroll
            for (int u = 0; u < 16; ++u) xs[u] *= sc;
            hi16_store_rn(xs, &Khi[r * SB + s * 16]);
        }
        {   // stage V TRANSPOSED (hi-only RN): thread = dim lane, keys w*16..+15
            float xs[16];
#pragma unroll
            for (int u = 0; u < 16; ++u) {
                int trow = stb[ck * 64 + w * 16 + u];     // wave-uniform
                xs[u] = vb[(size_t)trow * DIM + lane];    // coalesced 256B row
            }
            hi16_store_rn(xs, &Vhi[lane * SB + w * 16]);
        }
        __syncthreads();              // K, Vt, tk staged

        // dots: dt = q · K_hi^T  (2-term split: (qH+qL)*kH)
        floatx4 dt[4];
#pragma unroll
        for (int jt = 0; jt < 4; ++jt) dt[jt] = (floatx4){0.f, 0.f, 0.f, 0.f};
#pragma unroll
        for (int kb = 0; kb < 2; ++kb) {
#pragma unroll
            for (int jt = 0; jt < 4; ++jt) {
                short8 bH = *(const short8*)&Khi[(16 * jt + l15) * SB + kb * 32 + quad * 8];
                dt[jt] = __builtin_amdgcn_mfma_f32_16x16x32_bf16(qH[kb], bH, dt[jt], 0, 0, 0);
                dt[jt] = __builtin_amdgcn_mfma_f32_16x16x32_bf16(qL[kb], bH, dt[jt], 0, 0, 0);
            }
        }
        __syncthreads();              // all dots reads of K done -> P may overwrite

        // mask + exp (fp32) + wave-private P-hi write (RN) + denominator partials
#pragma unroll
        for (int jt = 0; jt < 4; ++jt) {
            int tkc = tk[16 * jt + l15];
#pragma unroll
            for (int r = 0; r < 4; ++r) {
                float p = (tqr[r] == tkc) ? 0.f : __expf(dt[jt][r] * 0.125f);
                Dacc[r] += p;
                int idx = (16 * w + quad * 4 + r) * SB + 16 * jt + l15;
                Phi[idx] = (short)((__float_as_uint(p) + 0x8000u) >> 16);
            }
        }

        // PV: O += P_hi·V_hi (A = own P strip -> no barrier; B = Vt hi)
#pragma unroll
        for (int kb = 0; kb < 2; ++kb) {
            short8 aH = *(const short8*)&Phi[(16 * w + l15) * SB + kb * 32 + quad * 8];
#pragma unroll
            for (int a = 0; a < 4; ++a) {
                short8 bH = *(const short8*)&Vhi[(16 * a + l15) * SB + kb * 32 + quad * 8];
                oacc[a] = __builtin_amdgcn_mfma_f32_16x16x32_bf16(aH, bH, oacc[a], 0, 0, 0);
            }
        }
    }

    // epilogue: scatter to token-major rows Obuf[((b*4096+t)*8 + h)*64 + d]
    // in fp16 (halved round-trip), h = c>>6.
    int h = c >> 6;
#pragma unroll
    for (int r = 0; r < 4; ++r) {
        int t = tqr[r];
        size_t rowb = ((size_t)(b * SEQ + t) * NHASH + h) * DIM;
#pragma unroll
        for (int a = 0; a < 4; ++a)
            Obuf[rowb + 16 * a + l15] = __float2half(oacc[a][r]);
    }
#pragma unroll
    for (int r = 0; r < 4; ++r) {
        float rs = Dacc[r];
        rs += __shfl_xor(rs, 1);
        rs += __shfl_xor(rs, 2);
        rs += __shfl_xor(rs, 4);
        rs += __shfl_xor(rs, 8);
        if (l15 == 0) Dbuf[(size_t)(b * SEQ + tqr[r]) * NHASH + h] = rs;
    }
}

// ---------------------------------------------------------------------------
// Kernel 4: out[b,t] = sum_h O_h / sum_h D_h -- streaming, fp16 numerator.
// Traffic: read 67 MB (Obuf) + 2 MB (Dbuf), write 16.8 MB.
// ---------------------------------------------------------------------------
__global__ __launch_bounds__(256) void lsh_combine_tok(
    const __half* __restrict__ Obuf, const float* __restrict__ Dbuf,
    float* __restrict__ out)
{
    int gid = blockIdx.x * 256 + threadIdx.x;   // (b*4096+t)*16 + d4
    int d4 = gid & 15;
    int bt = gid >> 4;

    const __half* op = Obuf + (size_t)bt * (NHASH * DIM) + d4 * 4;
    const float*  dp = Dbuf + (size_t)bt * NHASH;

    float4 n = make_float4(0.f, 0.f, 0.f, 0.f);
    float den = 0.f;
#pragma unroll
    for (int h = 0; h < NHASH; ++h) {
        uint2 u = *(const uint2*)(op + h * DIM);
        __half2 p01 = *(__half2*)&u.x;
        __half2 p23 = *(__half2*)&u.y;
        float2 f01 = __half22float2(p01);
        float2 f23 = __half22float2(p23);
        den += dp[h];
        n.x += f01.x; n.y += f01.y; n.z += f23.x; n.w += f23.y;
    }
    float invd = 1.0f / den;
    float4 r; r.x = n.x*invd; r.y = n.y*invd; r.z = n.z*invd; r.w = n.w*invd;
    ((float4*)out)[gid] = r;
}

extern "C" void kernel_launch(void* const* d_in, const int* in_sizes, int n_in,
                              void* d_out, int out_size, void* d_ws, size_t ws_size,
                              hipStream_t stream)
{
    const float* qk  = (const float*)d_in[0];
    const float* v   = (const float*)d_in[1];
    const float* rot = (const float*)d_in[2];
    float* out = (float*)d_out;

    char* w = (char*)d_ws;
    // workspace layout (73.2 MB):
    //   [0, 2MB)          buckets : int[16*8*4096]
    //   [2, 4MB)          st      : int[16*8*4096]
    //   [4MB, +67.1MB)    Obuf    : fp16[16*4096*8*64]  (token-major, h inner)
    //   then              Dbuf    : fp32[16*4096*8]
    int*    buckets = (int*)(w);
    int*    st      = (int*)(w + 2097152);
    __half* Obuf    = (__half*)(w + 4194304);
    float*  Dbuf    = (float*)(w + 4194304 + 67108864);

    lsh_hash_kernel<<<512, 256, 0, stream>>>(qk, rot, buckets);
    lsh_sort_kernel<<<128, 256, 0, stream>>>(buckets, st);
    lsh_attn_kernel<<<8192, 256, 0, stream>>>(qk, v, st, Obuf, Dbuf);
    lsh_combine_tok<<<4096, 256, 0, stream>>>(Obuf, Dbuf, out);
}